// Round 3
// baseline (409.848 us; speedup 1.0000x reference)
//
#include <hip/hip_runtime.h>

// Problem constants
constexpr int B  = 64;
constexpr int U  = 512;
constexpr int AE = 1024;
constexpr int UE = 256;
constexpr int A  = 256;     // head size
constexpr int KQ = AE + UE; // 1280

typedef _Float16 f16x8 __attribute__((ext_vector_type(8)));
typedef float    f32x4 __attribute__((ext_vector_type(4)));

// ---------------------------------------------------------------------------
// K0: cast+transpose weights to fp16 [N][K] so B-frags are k-contiguous
// ---------------------------------------------------------------------------
__global__ void prep(const float* __restrict__ Wq, const float* __restrict__ Wk,
                     _Float16* __restrict__ WqT, _Float16* __restrict__ WkT) {
    int idx = blockIdx.x * 256 + threadIdx.x;
    if (idx < KQ * A) {
        int k = idx >> 8, n = idx & 255;
        WqT[(size_t)n * KQ + k] = (_Float16)Wq[idx];
    } else {
        int j = idx - KQ * A;
        if (j < A * A) {
            int k = j >> 8, n = j & 255;
            WkT[(size_t)n * A + k] = (_Float16)Wk[j];
        }
    }
}

// ---------------------------------------------------------------------------
// K1/K2: LDS-free streaming GEMM. C[m][n] = concat(A1|A2)[m][k]*BT[n][k]+bias.
// No __syncthreads in the K-loop -> no vmcnt(0) drains; compiler pipelines
// global loads with fine-grained vmcnt across unrolled iterations.
// 256 thr / 4 waves; wave tile 32x128 (mt=2 x nt=8 of 16x16), block 64x256.
// A-frags: direct global fp32 loads in MFMA layout (16 rows x 128B lines,
// L1 merges the two float4s per row). B-frags: direct from L2-resident BT.
// Output fp16 in permuted layout [b=row>>9][c=col>>5][u=row&511][col&31].
// ---------------------------------------------------------------------------
__global__ __launch_bounds__(256, 2) void gemm(
    const float* __restrict__ A1, int s1, int split,
    const float* __restrict__ A2, int s2,
    const _Float16* __restrict__ BT,   // [256][Ktot] fp16
    const float* __restrict__ bias,    // [256]
    _Float16* __restrict__ Out,        // permuted, see above
    int Ktot)
{
    const int t    = threadIdx.x;
    const int lane = t & 63;
    const int w    = t >> 6;                    // 0..3
    const int lm   = lane & 15;
    const int lk   = (lane >> 4) * 8;           // k-offset of this lane's frag
    const int wm   = blockIdx.x * 64 + (w & 1) * 32;  // global row base
    const int wn   = (w >> 1) * 128;            // col base

    f32x4 acc[2][8] = {};

    const size_t r0 = wm + lm;
    const size_t r1 = wm + 16 + lm;

    #pragma unroll 2
    for (int k0 = 0; k0 < Ktot; k0 += 32) {
        const int kg = k0 + lk;
        f16x8 af[2], bf[8];
        #pragma unroll
        for (int mt = 0; mt < 2; mt++) {
            const size_t row = mt ? r1 : r0;
            const float* src = (kg < split) ? (A1 + row * (size_t)s1 + kg)
                                            : (A2 + row * (size_t)s2 + (kg - split));
            const float4 x = ((const float4*)src)[0];
            const float4 y = ((const float4*)src)[1];
            f16x8 hv;
            hv[0] = (_Float16)x.x; hv[1] = (_Float16)x.y;
            hv[2] = (_Float16)x.z; hv[3] = (_Float16)x.w;
            hv[4] = (_Float16)y.x; hv[5] = (_Float16)y.y;
            hv[6] = (_Float16)y.z; hv[7] = (_Float16)y.w;
            af[mt] = hv;
        }
        #pragma unroll
        for (int nt = 0; nt < 8; nt++)
            bf[nt] = *(const f16x8*)(BT + (size_t)(wn + nt * 16 + lm) * Ktot + kg);
        #pragma unroll
        for (int mt = 0; mt < 2; mt++)
            #pragma unroll
            for (int nt = 0; nt < 8; nt++)
                acc[mt][nt] = __builtin_amdgcn_mfma_f32_16x16x32_f16(
                    af[mt], bf[nt], acc[mt][nt], 0, 0, 0);
    }

    // epilogue: C layout col=lane&15, row=(lane>>4)*4+reg; permuted store
    const int rsub = (lane >> 4) * 4;
    #pragma unroll
    for (int nt = 0; nt < 8; nt++) {
        const int col = wn + nt * 16 + lm;
        const float bv = bias[col];
        const int c5 = col >> 5, c31 = col & 31;
        #pragma unroll
        for (int mt = 0; mt < 2; mt++)
            #pragma unroll
            for (int r = 0; r < 4; r++) {
                int row = wm + mt * 16 + rsub + r;
                int bb = row >> 9, u = row & 511;
                Out[(((size_t)bb * 8 + c5) * 512 + u) * 32 + c31] =
                    (_Float16)(acc[mt][nt][r] + bv);
            }
    }
}

// ---------------------------------------------------------------------------
// K3: block = (batch, 32 q-rows), 256 thr / 4 waves; wave = 32 rows x 128
// cols (waves partition the 512 cols). S = Qh Kh^T / 16, multiplicative
// mask, softmax in regs + small LDS cross-wave combine. No barriers in the
// d-chunk loop; Q/K frags loaded directly from permuted (L3-hot) Qh/Kh.
// ---------------------------------------------------------------------------
__global__ __launch_bounds__(256, 2) void attn(
    const _Float16* __restrict__ Qh, const _Float16* __restrict__ Kh,
    const int* __restrict__ nr_own_units, const int* __restrict__ nr_units_enemy,
    const int* __restrict__ nr_own_flags, float* __restrict__ Out)
{
    __shared__ float red[32][4];

    const int t    = threadIdx.x;
    const int lane = t & 63;
    const int w    = t >> 6;                 // 0..3
    const int lm   = lane & 15;
    const int lk   = (lane >> 4) * 8;
    const int b    = blockIdx.y;
    const int qbase = blockIdx.x * 32;
    const int wn   = w * 128;

    const int nf = nr_own_flags[b];
    const int nu = nr_own_units[b];
    const int ne = nr_units_enemy[b];

    const _Float16* Qb = Qh + (size_t)b * 8 * 512 * 32;
    const _Float16* Kb = Kh + (size_t)b * 8 * 512 * 32;

    f32x4 acc[2][8] = {};

    #pragma unroll 2
    for (int c = 0; c < 8; c++) {
        f16x8 qf[2], bf[8];
        #pragma unroll
        for (int mt = 0; mt < 2; mt++)
            qf[mt] = *(const f16x8*)(Qb + ((size_t)c * 512 + qbase + mt * 16 + lm) * 32 + lk);
        #pragma unroll
        for (int nt = 0; nt < 8; nt++)
            bf[nt] = *(const f16x8*)(Kb + ((size_t)c * 512 + wn + nt * 16 + lm) * 32 + lk);
        #pragma unroll
        for (int mt = 0; mt < 2; mt++)
            #pragma unroll
            for (int nt = 0; nt < 8; nt++)
                acc[mt][nt] = __builtin_amdgcn_mfma_f32_16x16x32_f16(
                    qf[mt], bf[nt], acc[mt][nt], 0, 0, 0);
    }

    // ---- mask + scale in registers
    const int rsub = (lane >> 4) * 4;
    #pragma unroll
    for (int mt = 0; mt < 2; mt++)
        #pragma unroll
        for (int nt = 0; nt < 8; nt++)
            #pragma unroll
            for (int r = 0; r < 4; r++) {
                int uq = qbase + mt * 16 + rsub + r;
                int col = wn + nt * 16 + lm;
                bool ok = (col < ne) && (uq >= nf) && (uq < nu);
                acc[mt][nt][r] = acc[mt][nt][r] * 0.0625f * (ok ? 1.0f : 1e-9f);
            }

    // ---- row max: in-lane over nt, across the 16-lane col group, cross-wave
    float mx[2][4];
    #pragma unroll
    for (int mt = 0; mt < 2; mt++)
        #pragma unroll
        for (int r = 0; r < 4; r++) {
            float m = acc[mt][0][r];
            #pragma unroll
            for (int nt = 1; nt < 8; nt++) m = fmaxf(m, acc[mt][nt][r]);
            #pragma unroll
            for (int off = 1; off <= 8; off <<= 1) m = fmaxf(m, __shfl_xor(m, off));
            mx[mt][r] = m;
        }
    if (lm == 0) {
        #pragma unroll
        for (int mt = 0; mt < 2; mt++)
            #pragma unroll
            for (int r = 0; r < 4; r++)
                red[mt * 16 + rsub + r][w] = mx[mt][r];
    }
    __syncthreads();
    #pragma unroll
    for (int mt = 0; mt < 2; mt++)
        #pragma unroll
        for (int r = 0; r < 4; r++) {
            f32x4 v = *(const f32x4*)(&red[mt * 16 + rsub + r][0]);
            mx[mt][r] = fmaxf(fmaxf(v[0], v[1]), fmaxf(v[2], v[3]));
        }
    __syncthreads();   // all reads done before red is reused for sums

    // ---- exp + row sum
    float sm[2][4];
    #pragma unroll
    for (int mt = 0; mt < 2; mt++)
        #pragma unroll
        for (int r = 0; r < 4; r++) {
            float s = 0.f;
            #pragma unroll
            for (int nt = 0; nt < 8; nt++) {
                float e = __expf(acc[mt][nt][r] - mx[mt][r]);
                acc[mt][nt][r] = e;
                s += e;
            }
            #pragma unroll
            for (int off = 1; off <= 8; off <<= 1) s += __shfl_xor(s, off);
            sm[mt][r] = s;
        }
    if (lm == 0) {
        #pragma unroll
        for (int mt = 0; mt < 2; mt++)
            #pragma unroll
            for (int r = 0; r < 4; r++)
                red[mt * 16 + rsub + r][w] = sm[mt][r];
    }
    __syncthreads();

    // ---- normalize + store
    #pragma unroll
    for (int mt = 0; mt < 2; mt++)
        #pragma unroll
        for (int r = 0; r < 4; r++) {
            int rl = mt * 16 + rsub + r;
            f32x4 v = *(const f32x4*)(&red[rl][0]);
            float inv = 1.0f / (v[0] + v[1] + v[2] + v[3]);
            float* orow = Out + ((size_t)b * 512 + qbase + rl) * 512 + wn + lm;
            #pragma unroll
            for (int nt = 0; nt < 8; nt++)
                orow[nt * 16] = acc[mt][nt][r] * inv;
        }
}

// ---------------------------------------------------------------------------
extern "C" void kernel_launch(void* const* d_in, const int* in_sizes, int n_in,
                              void* d_out, int out_size, void* d_ws, size_t ws_size,
                              hipStream_t stream) {
    const float* ar    = (const float*)d_in[0];   // [B,U,AE]
    const float* own   = (const float*)d_in[1];   // [B,U,UE]
    const float* enemy = (const float*)d_in[2];   // [B,U,UE]
    const int*   n_own   = (const int*)d_in[3];   // nr_own_units
    const int*   n_enemy = (const int*)d_in[4];   // nr_units_enemy
    const int*   n_flags = (const int*)d_in[5];   // nr_own_flags
    const float* Wq = (const float*)d_in[6];
    const float* bq = (const float*)d_in[7];
    const float* Wk = (const float*)d_in[8];
    const float* bk = (const float*)d_in[9];
    float* out = (float*)d_out;

    char* ws = (char*)d_ws;
    _Float16* WqT = (_Float16*)(ws);                       // 256x1280 fp16
    _Float16* WkT = (_Float16*)(ws + 655360);              // 256x256  fp16
    _Float16* Qh  = (_Float16*)(ws + 786432);              // [64][8][512][32] f16
    _Float16* Kh  = (_Float16*)(ws + 786432 + 16777216);   // [64][8][512][32] f16

    prep<<<dim3((KQ * A + A * A) / 256), dim3(256), 0, stream>>>(Wq, Wk, WqT, WkT);

    // Q = concat(ar, own) @ Wq + bq   (M=32768, K=1280)
    gemm<<<dim3(512), dim3(256), 0, stream>>>(ar, AE, AE, own, UE, WqT, bq, Qh, KQ);
    // K = enemy @ Wk + bk             (M=32768, K=256; split=0 -> A2 path)
    gemm<<<dim3(512), dim3(256), 0, stream>>>(enemy, UE, 0, enemy, UE, WkT, bk, Kh, A);

    attn<<<dim3(16, B), dim3(256), 0, stream>>>(Qh, Kh, n_own, n_enemy, n_flags, out);
}

// Round 4
// 358.533 us; speedup vs baseline: 1.1431x; 1.1431x over previous
//
#include <hip/hip_runtime.h>

// Problem constants
constexpr int B  = 64;
constexpr int U  = 512;
constexpr int AE = 1024;
constexpr int UE = 256;
constexpr int A  = 256;     // head size
constexpr int KQ = AE + UE; // 1280

typedef _Float16 f16x8 __attribute__((ext_vector_type(8)));
typedef float    f32x4 __attribute__((ext_vector_type(4)));

// ---------------------------------------------------------------------------
// K0: cast+transpose weights to fp16 [N][K] so B-frags are k-contiguous
// ---------------------------------------------------------------------------
__global__ void prep(const float* __restrict__ Wq, const float* __restrict__ Wk,
                     _Float16* __restrict__ WqT, _Float16* __restrict__ WkT) {
    int idx = blockIdx.x * 256 + threadIdx.x;
    if (idx < KQ * A) {
        int k = idx >> 8, n = idx & 255;
        WqT[(size_t)n * KQ + k] = (_Float16)Wq[idx];
    } else {
        int j = idx - KQ * A;
        if (j < A * A) {
            int k = j >> 8, n = j & 255;
            WkT[(size_t)n * A + k] = (_Float16)Wk[j];
        }
    }
}

// ---------------------------------------------------------------------------
// K1/K2: C[m][n] = concat(A1|A2)[m][k]*BT[n][k]+bias, fp16 out in permuted
// layout [b=row>>9][c=col>>5][u=row&511][col&31].
// 256 thr / 4 waves, BM=64 x BN=128, BK=64, single-buffer 24KB LDS,
// register prefetch. Grid 1024 blocks -> 4 blocks/CU resident: barrier
// drains of one block overlap with MFMA phases of the other three.
// Block pairs (bid>>1 equal) share the A tile -> L2/L3 reuse.
// LDS bank swizzle: chunk ^= (row>>1)&3 (2-way max = free).
// ---------------------------------------------------------------------------
__global__ __launch_bounds__(256, 4) void gemm(
    const float* __restrict__ A1, int s1, int split,
    const float* __restrict__ A2, int s2,
    const _Float16* __restrict__ BT,   // [256][Ktot] fp16
    const float* __restrict__ bias,    // [256]
    _Float16* __restrict__ Out,        // permuted, see above
    int Ktot)
{
    __shared__ __align__(16) _Float16 Al[2][64][32];    // 8 KB  (k-plane, row, 32)
    __shared__ __align__(16) _Float16 Bl[2][128][32];   // 16 KB

    const int t    = threadIdx.x;
    const int lane = t & 63;
    const int w    = t >> 6;                   // 0..3
    const int lm   = lane & 15;
    const int mbase = (blockIdx.x >> 1) * 64;
    const int nbase = (blockIdx.x & 1) * 128;

    const int wm  = (w & 1) * 32;              // wave row base (local)
    const int wnl = (w >> 1) * 64;             // wave col base (local, within 128)

    f32x4 acc[2][4] = {};

    // ---- A staging mapping: thread -> row ar, 16-float k-seg kh
    const int ar = t & 63;
    const int kh = t >> 6;                     // 0..3, k-offset kh*16
    const int ap = kh >> 1;                    // plane
    const size_t garow = mbase + ar;

    // ---- B staging mapping: thread -> row br, 32-f16 k-half bs (= plane)
    const int br = t >> 1;                     // 0..127
    const int bs = t & 1;                      // plane
    const size_t gbrow = nbase + br;

    float4 aR[4];      // 16 floats
    f16x8  bR[4];      // 32 f16

    auto loadA = [&](int k0) {
        int kg = k0 + kh * 16;
        const float* src = (kg < split) ? (A1 + garow * (size_t)s1 + kg)
                                        : (A2 + garow * (size_t)s2 + (kg - split));
        aR[0] = ((const float4*)src)[0];
        aR[1] = ((const float4*)src)[1];
        aR[2] = ((const float4*)src)[2];
        aR[3] = ((const float4*)src)[3];
    };
    auto loadB = [&](int k0) {
        const _Float16* src = BT + gbrow * (size_t)Ktot + k0 + bs * 32;
        bR[0] = ((const f16x8*)src)[0];
        bR[1] = ((const f16x8*)src)[1];
        bR[2] = ((const f16x8*)src)[2];
        bR[3] = ((const f16x8*)src)[3];
    };

    loadA(0);
    loadB(0);

    const int rsw = (lm >> 1) & 3;             // read-side swizzle
    const int nk = Ktot >> 6;
    for (int kb = 0; kb < nk; kb++) {
        __syncthreads();   // prev iter's LDS readers done
        {   // publish staged regs (compiler inserts the vmcnt wait here)
            #pragma unroll
            for (int j = 0; j < 2; j++) {
                const float4 x = aR[j * 2], y = aR[j * 2 + 1];
                f16x8 hv;
                hv[0] = (_Float16)x.x; hv[1] = (_Float16)x.y;
                hv[2] = (_Float16)x.z; hv[3] = (_Float16)x.w;
                hv[4] = (_Float16)y.x; hv[5] = (_Float16)y.y;
                hv[6] = (_Float16)y.z; hv[7] = (_Float16)y.w;
                int c = (kh & 1) * 2 + j;                       // chunk within plane
                *(f16x8*)(&Al[ap][ar][(c ^ ((ar >> 1) & 3)) * 8]) = hv;
            }
            #pragma unroll
            for (int j = 0; j < 4; j++)
                *(f16x8*)(&Bl[bs][br][(j ^ ((br >> 1) & 3)) * 8]) = bR[j];
        }
        __syncthreads();
        if (kb + 1 < nk) { loadA(kb * 64 + 64); loadB(kb * 64 + 64); }
        #pragma unroll
        for (int p = 0; p < 2; p++) {
            f16x8 af[2], bf[4];
            #pragma unroll
            for (int mt = 0; mt < 2; mt++)
                af[mt] = *(const f16x8*)(&Al[p][wm + mt * 16 + lm][((lane >> 4) ^ rsw) * 8]);
            #pragma unroll
            for (int nt = 0; nt < 4; nt++)
                bf[nt] = *(const f16x8*)(&Bl[p][wnl + nt * 16 + lm][((lane >> 4) ^ rsw) * 8]);
            #pragma unroll
            for (int mt = 0; mt < 2; mt++)
                #pragma unroll
                for (int nt = 0; nt < 4; nt++)
                    acc[mt][nt] = __builtin_amdgcn_mfma_f32_16x16x32_f16(
                        af[mt], bf[nt], acc[mt][nt], 0, 0, 0);
        }
    }

    // epilogue: C layout col=lane&15, row=(lane>>4)*4+reg; permuted store
    const int rsub = (lane >> 4) * 4;
    #pragma unroll
    for (int nt = 0; nt < 4; nt++) {
        const int col = nbase + wnl + nt * 16 + lm;
        const float bv = bias[col];
        const int c5 = col >> 5, c31 = col & 31;
        #pragma unroll
        for (int mt = 0; mt < 2; mt++)
            #pragma unroll
            for (int r = 0; r < 4; r++) {
                int row = mbase + wm + mt * 16 + rsub + r;
                int bb = row >> 9, u = row & 511;
                Out[(((size_t)bb * 8 + c5) * 512 + u) * 32 + c31] =
                    (_Float16)(acc[mt][nt][r] + bv);
            }
    }
}

// ---------------------------------------------------------------------------
// K3: block = (batch, 32 q-rows), 256 thr / 4 waves; wave = 32 rows x 128
// cols. S = Qh Kh^T / 16, multiplicative mask, softmax in regs + small LDS
// cross-wave combine. No barriers in the d-chunk loop; frag loads from the
// permuted Qh/Kh are fully coalesced (64 lanes x 16B = one 1KB region).
// ---------------------------------------------------------------------------
__global__ __launch_bounds__(256, 4) void attn(
    const _Float16* __restrict__ Qh, const _Float16* __restrict__ Kh,
    const int* __restrict__ nr_own_units, const int* __restrict__ nr_units_enemy,
    const int* __restrict__ nr_own_flags, float* __restrict__ Out)
{
    __shared__ float red[32][4];

    const int t    = threadIdx.x;
    const int lane = t & 63;
    const int w    = t >> 6;                 // 0..3
    const int lm   = lane & 15;
    const int lk   = (lane >> 4) * 8;
    const int b    = blockIdx.y;
    const int qbase = blockIdx.x * 32;
    const int wn   = w * 128;

    const int nf = nr_own_flags[b];
    const int nu = nr_own_units[b];
    const int ne = nr_units_enemy[b];

    const _Float16* Qb = Qh + (size_t)b * 8 * 512 * 32;
    const _Float16* Kb = Kh + (size_t)b * 8 * 512 * 32;

    f32x4 acc[2][8] = {};

    #pragma unroll 2
    for (int c = 0; c < 8; c++) {
        f16x8 qf[2], bf[8];
        #pragma unroll
        for (int mt = 0; mt < 2; mt++)
            qf[mt] = *(const f16x8*)(Qb + ((size_t)c * 512 + qbase + mt * 16 + lm) * 32 + lk);
        #pragma unroll
        for (int nt = 0; nt < 8; nt++)
            bf[nt] = *(const f16x8*)(Kb + ((size_t)c * 512 + wn + nt * 16 + lm) * 32 + lk);
        #pragma unroll
        for (int mt = 0; mt < 2; mt++)
            #pragma unroll
            for (int nt = 0; nt < 8; nt++)
                acc[mt][nt] = __builtin_amdgcn_mfma_f32_16x16x32_f16(
                    qf[mt], bf[nt], acc[mt][nt], 0, 0, 0);
    }

    // ---- mask + scale in registers
    const int rsub = (lane >> 4) * 4;
    #pragma unroll
    for (int mt = 0; mt < 2; mt++)
        #pragma unroll
        for (int nt = 0; nt < 8; nt++)
            #pragma unroll
            for (int r = 0; r < 4; r++) {
                int uq = qbase + mt * 16 + rsub + r;
                int col = wn + nt * 16 + lm;
                bool ok = (col < ne) && (uq >= nf) && (uq < nu);
                acc[mt][nt][r] = acc[mt][nt][r] * 0.0625f * (ok ? 1.0f : 1e-9f);
            }

    // ---- row max: in-lane over nt, across the 16-lane col group, cross-wave
    float mx[2][4];
    #pragma unroll
    for (int mt = 0; mt < 2; mt++)
        #pragma unroll
        for (int r = 0; r < 4; r++) {
            float m = acc[mt][0][r];
            #pragma unroll
            for (int nt = 1; nt < 8; nt++) m = fmaxf(m, acc[mt][nt][r]);
            #pragma unroll
            for (int off = 1; off <= 8; off <<= 1) m = fmaxf(m, __shfl_xor(m, off));
            mx[mt][r] = m;
        }
    if (lm == 0) {
        #pragma unroll
        for (int mt = 0; mt < 2; mt++)
            #pragma unroll
            for (int r = 0; r < 4; r++)
                red[mt * 16 + rsub + r][w] = mx[mt][r];
    }
    __syncthreads();
    #pragma unroll
    for (int mt = 0; mt < 2; mt++)
        #pragma unroll
        for (int r = 0; r < 4; r++) {
            f32x4 v = *(const f32x4*)(&red[mt * 16 + rsub + r][0]);
            mx[mt][r] = fmaxf(fmaxf(v[0], v[1]), fmaxf(v[2], v[3]));
        }
    __syncthreads();   // all reads done before red is reused for sums

    // ---- exp + row sum
    float sm[2][4];
    #pragma unroll
    for (int mt = 0; mt < 2; mt++)
        #pragma unroll
        for (int r = 0; r < 4; r++) {
            float s = 0.f;
            #pragma unroll
            for (int nt = 0; nt < 8; nt++) {
                float e = __expf(acc[mt][nt][r] - mx[mt][r]);
                acc[mt][nt][r] = e;
                s += e;
            }
            #pragma unroll
            for (int off = 1; off <= 8; off <<= 1) s += __shfl_xor(s, off);
            sm[mt][r] = s;
        }
    if (lm == 0) {
        #pragma unroll
        for (int mt = 0; mt < 2; mt++)
            #pragma unroll
            for (int r = 0; r < 4; r++)
                red[mt * 16 + rsub + r][w] = sm[mt][r];
    }
    __syncthreads();

    // ---- normalize + store
    #pragma unroll
    for (int mt = 0; mt < 2; mt++)
        #pragma unroll
        for (int r = 0; r < 4; r++) {
            int rl = mt * 16 + rsub + r;
            f32x4 v = *(const f32x4*)(&red[rl][0]);
            float inv = 1.0f / (v[0] + v[1] + v[2] + v[3]);
            float* orow = Out + ((size_t)b * 512 + qbase + rl) * 512 + wn + lm;
            #pragma unroll
            for (int nt = 0; nt < 8; nt++)
                orow[nt * 16] = acc[mt][nt][r] * inv;
        }
}

// ---------------------------------------------------------------------------
extern "C" void kernel_launch(void* const* d_in, const int* in_sizes, int n_in,
                              void* d_out, int out_size, void* d_ws, size_t ws_size,
                              hipStream_t stream) {
    const float* ar    = (const float*)d_in[0];   // [B,U,AE]
    const float* own   = (const float*)d_in[1];   // [B,U,UE]
    const float* enemy = (const float*)d_in[2];   // [B,U,UE]
    const int*   n_own   = (const int*)d_in[3];   // nr_own_units
    const int*   n_enemy = (const int*)d_in[4];   // nr_units_enemy
    const int*   n_flags = (const int*)d_in[5];   // nr_own_flags
    const float* Wq = (const float*)d_in[6];
    const float* bq = (const float*)d_in[7];
    const float* Wk = (const float*)d_in[8];
    const float* bk = (const float*)d_in[9];
    float* out = (float*)d_out;

    char* ws = (char*)d_ws;
    _Float16* WqT = (_Float16*)(ws);                       // 256x1280 fp16
    _Float16* WkT = (_Float16*)(ws + 655360);              // 256x256  fp16
    _Float16* Qh  = (_Float16*)(ws + 786432);              // [64][8][512][32] f16
    _Float16* Kh  = (_Float16*)(ws + 786432 + 16777216);   // [64][8][512][32] f16

    prep<<<dim3((KQ * A + A * A) / 256), dim3(256), 0, stream>>>(Wq, Wk, WqT, WkT);

    // Q = concat(ar, own) @ Wq + bq   (M=32768, K=1280) — 1024 blocks
    gemm<<<dim3(1024), dim3(256), 0, stream>>>(ar, AE, AE, own, UE, WqT, bq, Qh, KQ);
    // K = enemy @ Wk + bk             (M=32768, K=256; split=0 -> A2 path)
    gemm<<<dim3(1024), dim3(256), 0, stream>>>(enemy, UE, 0, enemy, UE, WkT, bk, Kh, A);

    attn<<<dim3(16, B), dim3(256), 0, stream>>>(Qh, Kh, n_own, n_enemy, n_flags, out);
}

// Round 5
// 333.128 us; speedup vs baseline: 1.2303x; 1.0763x over previous
//
#include <hip/hip_runtime.h>

// Problem constants
constexpr int B  = 64;
constexpr int U  = 512;
constexpr int AE = 1024;
constexpr int UE = 256;
constexpr int A  = 256;     // head size
constexpr int KQ = AE + UE; // 1280

typedef _Float16 f16x8 __attribute__((ext_vector_type(8)));
typedef float    f32x4 __attribute__((ext_vector_type(4)));

// ---------------------------------------------------------------------------
// K0: cast+transpose weights to fp16 [N][K] so B-frags are k-contiguous
// ---------------------------------------------------------------------------
__global__ void prep(const float* __restrict__ Wq, const float* __restrict__ Wk,
                     _Float16* __restrict__ WqT, _Float16* __restrict__ WkT) {
    int idx = blockIdx.x * 256 + threadIdx.x;
    if (idx < KQ * A) {
        int k = idx >> 8, n = idx & 255;
        WqT[(size_t)n * KQ + k] = (_Float16)Wq[idx];
    } else {
        int j = idx - KQ * A;
        if (j < A * A) {
            int k = j >> 8, n = j & 255;
            WkT[(size_t)n * A + k] = (_Float16)Wk[j];
        }
    }
}

// ---------------------------------------------------------------------------
// K1/K2: C[m][n] = concat(A1|A2)[m][k]*BT[n][k]+bias, fp16 out in permuted
// layout [b=row>>9][c=col>>5][u=row&511][col&31].
// BM=128 x BN=256 (full N: A read exactly ONCE; B re-read count = M/128),
// BK=64, 512 thr / 8 waves, wave tile 64x64 (acc 4x4), 48 KB LDS single buf,
// register prefetch. Grid = 256 blocks = exactly 1/CU: per-CU traffic
// (the binding constraint, ~9.5 B/cyc/CU measured r2-r4) is minimized.
// LDS bank swizzle: chunk ^= (row>>1)&3 (2-way max = free).
// ---------------------------------------------------------------------------
__global__ __launch_bounds__(512, 1) void gemm(
    const float* __restrict__ A1, int s1, int split,
    const float* __restrict__ A2, int s2,
    const _Float16* __restrict__ BT,   // [256][Ktot] fp16
    const float* __restrict__ bias,    // [256]
    _Float16* __restrict__ Out,        // permuted, see above
    int Ktot)
{
    __shared__ __align__(16) _Float16 Al[2][128][32];   // 16 KB (k-plane, row, 32)
    __shared__ __align__(16) _Float16 Bl[2][256][32];   // 32 KB

    const int t    = threadIdx.x;
    const int lane = t & 63;
    const int w    = t >> 6;                   // 0..7
    const int lm   = lane & 15;
    const int mbase = blockIdx.x * 128;

    const int wm = (w & 1) * 64;               // wave row base (local)
    const int wn = (w >> 1) * 64;              // wave col base

    f32x4 acc[4][4] = {};

    // ---- A staging: thread -> row ar (0..127), 16-float k-seg as (0..3)
    const int ar = t >> 2;
    const int as = t & 3;                      // k-offset as*16
    const int ap = as >> 1;                    // plane
    const size_t garow = mbase + ar;

    // ---- B staging: thread -> row br (0..255), 32-f16 k-half bs (= plane)
    const int br = t >> 1;
    const int bs = t & 1;

    float4 aR[4];      // 16 floats
    f16x8  bR[4];      // 32 f16

    auto loadA = [&](int k0) {
        int kg = k0 + as * 16;    // split (1024) is a multiple of 16 -> no straddle
        const float* src = (kg < split) ? (A1 + garow * (size_t)s1 + kg)
                                        : (A2 + garow * (size_t)s2 + (kg - split));
        aR[0] = ((const float4*)src)[0];
        aR[1] = ((const float4*)src)[1];
        aR[2] = ((const float4*)src)[2];
        aR[3] = ((const float4*)src)[3];
    };
    auto loadB = [&](int k0) {
        const _Float16* src = BT + (size_t)br * Ktot + k0 + bs * 32;
        bR[0] = ((const f16x8*)src)[0];
        bR[1] = ((const f16x8*)src)[1];
        bR[2] = ((const f16x8*)src)[2];
        bR[3] = ((const f16x8*)src)[3];
    };

    loadA(0);
    loadB(0);

    const int rsw = (lm >> 1) & 3;             // read-side swizzle
    const int nk = Ktot >> 6;
    for (int kb = 0; kb < nk; kb++) {
        __syncthreads();   // prev iter's LDS readers done
        {   // publish staged regs (compiler inserts the vmcnt wait here)
            #pragma unroll
            for (int j = 0; j < 2; j++) {
                const float4 x = aR[j * 2], y = aR[j * 2 + 1];
                f16x8 hv;
                hv[0] = (_Float16)x.x; hv[1] = (_Float16)x.y;
                hv[2] = (_Float16)x.z; hv[3] = (_Float16)x.w;
                hv[4] = (_Float16)y.x; hv[5] = (_Float16)y.y;
                hv[6] = (_Float16)y.z; hv[7] = (_Float16)y.w;
                int c = (as & 1) * 2 + j;                      // chunk within plane
                *(f16x8*)(&Al[ap][ar][(c ^ ((ar >> 1) & 3)) * 8]) = hv;
            }
            #pragma unroll
            for (int j = 0; j < 4; j++)
                *(f16x8*)(&Bl[bs][br][(j ^ ((br >> 1) & 3)) * 8]) = bR[j];
        }
        __syncthreads();
        if (kb + 1 < nk) { loadA(kb * 64 + 64); loadB(kb * 64 + 64); }
        #pragma unroll
        for (int p = 0; p < 2; p++) {
            f16x8 af[4], bf[4];
            #pragma unroll
            for (int mt = 0; mt < 4; mt++)
                af[mt] = *(const f16x8*)(&Al[p][wm + mt * 16 + lm][((lane >> 4) ^ rsw) * 8]);
            #pragma unroll
            for (int nt = 0; nt < 4; nt++)
                bf[nt] = *(const f16x8*)(&Bl[p][wn + nt * 16 + lm][((lane >> 4) ^ rsw) * 8]);
            #pragma unroll
            for (int mt = 0; mt < 4; mt++)
                #pragma unroll
                for (int nt = 0; nt < 4; nt++)
                    acc[mt][nt] = __builtin_amdgcn_mfma_f32_16x16x32_f16(
                        af[mt], bf[nt], acc[mt][nt], 0, 0, 0);
        }
    }

    // epilogue: C layout col=lane&15, row=(lane>>4)*4+reg; permuted store
    const int rsub = (lane >> 4) * 4;
    #pragma unroll
    for (int nt = 0; nt < 4; nt++) {
        const int col = wn + nt * 16 + lm;
        const float bv = bias[col];
        const int c5 = col >> 5, c31 = col & 31;
        #pragma unroll
        for (int mt = 0; mt < 4; mt++)
            #pragma unroll
            for (int r = 0; r < 4; r++) {
                int row = mbase + wm + mt * 16 + rsub + r;
                int bb = row >> 9, u = row & 511;
                Out[(((size_t)bb * 8 + c5) * 512 + u) * 32 + c31] =
                    (_Float16)(acc[mt][nt][r] + bv);
            }
    }
}

// ---------------------------------------------------------------------------
// K3: block = (batch, 64 q-rows), 512 thr / 8 waves; wave = 32 rows x 128
// cols (2x4 wave grid). S = Qh Kh^T / 16, multiplicative mask, register
// softmax + small LDS cross-wave combine. Q tile (32 KB) staged once; K
// streamed in 8 chunks of 32-d via reg-prefetch into single-buffer LDS
// (dedups the 2-4x fragment re-requests an LDS-free version pays).
// ---------------------------------------------------------------------------
__global__ __launch_bounds__(512, 2) void attn(
    const _Float16* __restrict__ Qh, const _Float16* __restrict__ Kh,
    const int* __restrict__ nr_own_units, const int* __restrict__ nr_units_enemy,
    const int* __restrict__ nr_own_flags, float* __restrict__ Out)
{
    __shared__ __align__(16) _Float16 Ql[8][64][32];   // 32 KB
    __shared__ __align__(16) _Float16 Kl[512][32];     // 32 KB
    __shared__ float red[64][4];

    const int t    = threadIdx.x;
    const int lane = t & 63;
    const int w    = t >> 6;                 // 0..7
    const int lm   = lane & 15;
    const int b    = blockIdx.y;
    const int qbase = blockIdx.x * 64;

    const int wm = (w & 1) * 32;             // wave row base (0/32)
    const int wn = (w >> 1) * 128;           // wave col base (0..384)

    const int nf = nr_own_flags[b];
    const int nu = nr_own_units[b];
    const int ne = nr_units_enemy[b];

    // ---- stage Q once: [8 planes][64 rows][32], swizzled
    {
        f16x8 qreg[4];
        #pragma unroll
        for (int j = 0; j < 4; j++) {
            int s = j * 512 + t;
            int p = s >> 8, row = (s & 255) >> 2, cq = s & 3;
            qreg[j] = *(const f16x8*)(Qh + (((size_t)b * 8 + p) * 512 + qbase + row) * 32 + cq * 8);
        }
        #pragma unroll
        for (int j = 0; j < 4; j++) {
            int s = j * 512 + t;
            int p = s >> 8, row = (s & 255) >> 2, cq = s & 3;
            *(f16x8*)(&Ql[p][row][(cq ^ ((row >> 1) & 3)) * 8]) = qreg[j];
        }
    }

    // ---- K chunk staging: thread t -> row t, 4 chunks (64 B contiguous)
    const _Float16* Kb = Kh + (size_t)b * 8 * 512 * 32;
    f16x8 kreg[4];
    auto loadK = [&](int c) {
        const _Float16* src = Kb + ((size_t)c * 512 + t) * 32;
        kreg[0] = ((const f16x8*)src)[0];
        kreg[1] = ((const f16x8*)src)[1];
        kreg[2] = ((const f16x8*)src)[2];
        kreg[3] = ((const f16x8*)src)[3];
    };
    loadK(0);

    f32x4 acc[2][8] = {};
    const int rsw = (lm >> 1) & 3;
    for (int c = 0; c < 8; c++) {
        __syncthreads();   // c==0: Ql published; else: prev Kl readers done
        #pragma unroll
        for (int j = 0; j < 4; j++)
            *(f16x8*)(&Kl[t][(j ^ ((t >> 1) & 3)) * 8]) = kreg[j];
        __syncthreads();
        if (c < 7) loadK(c + 1);
        f16x8 af[2], bf[8];
        #pragma unroll
        for (int mt = 0; mt < 2; mt++)
            af[mt] = *(const f16x8*)(&Ql[c][wm + mt * 16 + lm][((lane >> 4) ^ rsw) * 8]);
        #pragma unroll
        for (int nt = 0; nt < 8; nt++)
            bf[nt] = *(const f16x8*)(&Kl[wn + nt * 16 + lm][((lane >> 4) ^ rsw) * 8]);
        #pragma unroll
        for (int mt = 0; mt < 2; mt++)
            #pragma unroll
            for (int nt = 0; nt < 8; nt++)
                acc[mt][nt] = __builtin_amdgcn_mfma_f32_16x16x32_f16(
                    af[mt], bf[nt], acc[mt][nt], 0, 0, 0);
    }

    // ---- mask + scale in registers
    const int rsub = (lane >> 4) * 4;
    #pragma unroll
    for (int mt = 0; mt < 2; mt++)
        #pragma unroll
        for (int nt = 0; nt < 8; nt++)
            #pragma unroll
            for (int r = 0; r < 4; r++) {
                int uq = qbase + wm + mt * 16 + rsub + r;
                int col = wn + nt * 16 + lm;
                bool ok = (col < ne) && (uq >= nf) && (uq < nu);
                acc[mt][nt][r] = acc[mt][nt][r] * 0.0625f * (ok ? 1.0f : 1e-9f);
            }

    // ---- row max: in-lane over nt, across 16-lane col group, cross-wave
    float mx[2][4];
    #pragma unroll
    for (int mt = 0; mt < 2; mt++)
        #pragma unroll
        for (int r = 0; r < 4; r++) {
            float m = acc[mt][0][r];
            #pragma unroll
            for (int nt = 1; nt < 8; nt++) m = fmaxf(m, acc[mt][nt][r]);
            #pragma unroll
            for (int off = 1; off <= 8; off <<= 1) m = fmaxf(m, __shfl_xor(m, off));
            mx[mt][r] = m;
        }
    if (lm == 0) {
        #pragma unroll
        for (int mt = 0; mt < 2; mt++)
            #pragma unroll
            for (int r = 0; r < 4; r++)
                red[wm + mt * 16 + rsub + r][w >> 1] = mx[mt][r];
    }
    __syncthreads();
    #pragma unroll
    for (int mt = 0; mt < 2; mt++)
        #pragma unroll
        for (int r = 0; r < 4; r++) {
            f32x4 v = *(const f32x4*)(&red[wm + mt * 16 + rsub + r][0]);
            mx[mt][r] = fmaxf(fmaxf(v[0], v[1]), fmaxf(v[2], v[3]));
        }
    __syncthreads();   // all reads done before red is reused for sums

    // ---- exp + row sum
    float sm[2][4];
    #pragma unroll
    for (int mt = 0; mt < 2; mt++)
        #pragma unroll
        for (int r = 0; r < 4; r++) {
            float s = 0.f;
            #pragma unroll
            for (int nt = 0; nt < 8; nt++) {
                float e = __expf(acc[mt][nt][r] - mx[mt][r]);
                acc[mt][nt][r] = e;
                s += e;
            }
            #pragma unroll
            for (int off = 1; off <= 8; off <<= 1) s += __shfl_xor(s, off);
            sm[mt][r] = s;
        }
    if (lm == 0) {
        #pragma unroll
        for (int mt = 0; mt < 2; mt++)
            #pragma unroll
            for (int r = 0; r < 4; r++)
                red[wm + mt * 16 + rsub + r][w >> 1] = sm[mt][r];
    }
    __syncthreads();

    // ---- normalize + store
    #pragma unroll
    for (int mt = 0; mt < 2; mt++)
        #pragma unroll
        for (int r = 0; r < 4; r++) {
            int rl = wm + mt * 16 + rsub + r;
            f32x4 v = *(const f32x4*)(&red[rl][0]);
            float inv = 1.0f / (v[0] + v[1] + v[2] + v[3]);
            float* orow = Out + ((size_t)b * 512 + qbase + rl) * 512 + wn + lm;
            #pragma unroll
            for (int nt = 0; nt < 8; nt++)
                orow[nt * 16] = acc[mt][nt][r] * inv;
        }
}

// ---------------------------------------------------------------------------
extern "C" void kernel_launch(void* const* d_in, const int* in_sizes, int n_in,
                              void* d_out, int out_size, void* d_ws, size_t ws_size,
                              hipStream_t stream) {
    const float* ar    = (const float*)d_in[0];   // [B,U,AE]
    const float* own   = (const float*)d_in[1];   // [B,U,UE]
    const float* enemy = (const float*)d_in[2];   // [B,U,UE]
    const int*   n_own   = (const int*)d_in[3];   // nr_own_units
    const int*   n_enemy = (const int*)d_in[4];   // nr_units_enemy
    const int*   n_flags = (const int*)d_in[5];   // nr_own_flags
    const float* Wq = (const float*)d_in[6];
    const float* bq = (const float*)d_in[7];
    const float* Wk = (const float*)d_in[8];
    const float* bk = (const float*)d_in[9];
    float* out = (float*)d_out;

    char* ws = (char*)d_ws;
    _Float16* WqT = (_Float16*)(ws);                       // 256x1280 fp16
    _Float16* WkT = (_Float16*)(ws + 655360);              // 256x256  fp16
    _Float16* Qh  = (_Float16*)(ws + 786432);              // [64][8][512][32] f16
    _Float16* Kh  = (_Float16*)(ws + 786432 + 16777216);   // [64][8][512][32] f16

    prep<<<dim3((KQ * A + A * A) / 256), dim3(256), 0, stream>>>(Wq, Wk, WqT, WkT);

    // Q = concat(ar, own) @ Wq + bq   (M=32768, K=1280) — 256 blocks, 1/CU
    gemm<<<dim3(256), dim3(512), 0, stream>>>(ar, AE, AE, own, UE, WqT, bq, Qh, KQ);
    // K = enemy @ Wk + bk             (M=32768, K=256; split=0 -> A2 path)
    gemm<<<dim3(256), dim3(512), 0, stream>>>(enemy, UE, 0, enemy, UE, WkT, bk, Kh, A);

    attn<<<dim3(8, B), dim3(512), 0, stream>>>(Qh, Kh, n_own, n_enemy, n_flags, out);
}